// Round 1
// baseline (386.493 us; speedup 1.0000x reference)
//
#include <hip/hip_runtime.h>

#define NWIN 1024
#define LTOK 256
#define EMB  192
#define NPAT 64
#define NHEAD 6
#define HDIM 32
#define SCALE 0.08838834764831845f
#define LN_EPS 1e-5f

typedef float f32x4 __attribute__((ext_vector_type(4)));
typedef short s16x8 __attribute__((ext_vector_type(8)));

// ---- LDS layout (bytes) ----
#define OFF_PRE 0              // [256][192] bf16, row stride 384B, swz ((t&7)<<4)
#define OFF_KH  98304          // [64][128]  bf16, row stride 256B, swz ((p&7)<<4)
#define OFF_VT  114688         // [128][64]  bf16, row stride 128B, swz ((sc&7)<<4)
#define OFF_PB  131072         // [64][64]   bf16, row stride 128B, swz ((q&7)<<4)
#define OFF_SB  139264         // [64] rows x 272B f32 (68 dwords/row)
#define OFF_ST  156672         // stats: 6 x 64 f32 (muq,rsq,muk,rsk,muv,rsv)
#define OFF_BH  158208         // bias_h: 225 f32 (padded to 960B)
#define SMEM_BYTES 159168
#define OFF_WL  OFF_KH         // proj W half [96][192] bf16, stride 384B, swz ((o&7)<<4)

__device__ __forceinline__ unsigned short f2bf(float f) {
    unsigned u = __float_as_uint(f);
    u += 0x7fffu + ((u >> 16) & 1u);
    return (unsigned short)(u >> 16);
}

__device__ __forceinline__ int tok_of(int p, int s) {
    // t = wh*32 + sh*16 + ww*2 + sw ; p = wh*8+ww, s = sh*2+sw
    return ((p >> 3) << 5) + ((s >> 1) << 4) + ((p & 7) << 1) + (s & 1);
}

__device__ __forceinline__ f32x4 mfma16(s16x8 a, s16x8 b, f32x4 c) {
    return __builtin_amdgcn_mfma_f32_16x16x32_bf16(a, b, c, 0, 0, 0);
}

__device__ __forceinline__ s16x8 ln_pack8(const float* __restrict__ x,
                                          float mu, float rs,
                                          const float* __restrict__ wl,
                                          const float* __restrict__ bl,
                                          float scale) {
    f32x4 a  = *(const f32x4*)x;
    f32x4 b  = *(const f32x4*)(x + 4);
    f32x4 w0 = *(const f32x4*)wl;
    f32x4 w1 = *(const f32x4*)(wl + 4);
    f32x4 c0 = *(const f32x4*)bl;
    f32x4 c1 = *(const f32x4*)(bl + 4);
    s16x8 r;
    r[0] = (short)f2bf(((a[0]-mu)*rs*w0[0] + c0[0])*scale);
    r[1] = (short)f2bf(((a[1]-mu)*rs*w0[1] + c0[1])*scale);
    r[2] = (short)f2bf(((a[2]-mu)*rs*w0[2] + c0[2])*scale);
    r[3] = (short)f2bf(((a[3]-mu)*rs*w0[3] + c0[3])*scale);
    r[4] = (short)f2bf(((b[0]-mu)*rs*w1[0] + c1[0])*scale);
    r[5] = (short)f2bf(((b[1]-mu)*rs*w1[1] + c1[1])*scale);
    r[6] = (short)f2bf(((b[2]-mu)*rs*w1[2] + c1[2])*scale);
    r[7] = (short)f2bf(((b[3]-mu)*rs*w1[3] + c1[3])*scale);
    return r;
}

__device__ __forceinline__ void ln_f8(const float* __restrict__ x,
                                      float mu, float rs,
                                      const float* __restrict__ wl,
                                      const float* __restrict__ bl,
                                      float* o) {
    f32x4 a  = *(const f32x4*)x;
    f32x4 b  = *(const f32x4*)(x + 4);
    f32x4 w0 = *(const f32x4*)wl;
    f32x4 w1 = *(const f32x4*)(wl + 4);
    f32x4 c0 = *(const f32x4*)bl;
    f32x4 c1 = *(const f32x4*)(bl + 4);
    o[0] = (a[0]-mu)*rs*w0[0] + c0[0];
    o[1] = (a[1]-mu)*rs*w0[1] + c0[1];
    o[2] = (a[2]-mu)*rs*w0[2] + c0[2];
    o[3] = (a[3]-mu)*rs*w0[3] + c0[3];
    o[4] = (b[0]-mu)*rs*w1[0] + c1[0];
    o[5] = (b[1]-mu)*rs*w1[1] + c1[1];
    o[6] = (b[2]-mu)*rs*w1[2] + c1[2];
    o[7] = (b[3]-mu)*rs*w1[3] + c1[3];
}

__global__ __launch_bounds__(512, 2) void dwa_kernel(
    const float* __restrict__ q_g, const float* __restrict__ k_g,
    const float* __restrict__ v_g, const float* __restrict__ mask_g,
    const float* __restrict__ lnqw, const float* __restrict__ lnqb,
    const float* __restrict__ lnkw, const float* __restrict__ lnkb,
    const float* __restrict__ lnvw, const float* __restrict__ lnvb,
    const float* __restrict__ btab, const float* __restrict__ pw,
    float* __restrict__ out_g)
{
    __shared__ __align__(16) char smem[SMEM_BYTES];

    const int tid  = threadIdx.x;
    const int lane = tid & 63;
    const int wv   = tid >> 6;
    const int win  = blockIdx.x;
    const size_t wbase = (size_t)win * LTOK * EMB;

    float* stats = (float*)(smem + OFF_ST);
    float* muq = stats;       float* rsq = stats + 64;
    float* muk = stats + 128; float* rsk = stats + 192;
    float* muv = stats + 256; float* rsv = stats + 320;
    float* biash = (float*)(smem + OFF_BH);

    // ---------------- Phase 1: LN stats for q,k,v ----------------
    {
        const float* tens[3] = {q_g, k_g, v_g};
        float* part = (float*)(smem + OFF_SB);   // [256 tokens][2 halves][2]
        const int t = tid >> 1, half = tid & 1;
        for (int x = 0; x < 3; ++x) {
            const f32x4* ptr = (const f32x4*)(tens[x] + wbase + t * EMB + half * 96);
            float s1 = 0.f, s2 = 0.f;
            #pragma unroll
            for (int i = 0; i < 24; ++i) {
                f32x4 v = ptr[i];
                s1 += v[0] + v[1] + v[2] + v[3];
                s2 += v[0]*v[0] + v[1]*v[1] + v[2]*v[2] + v[3]*v[3];
            }
            part[(t*2 + half)*2 + 0] = s1;
            part[(t*2 + half)*2 + 1] = s2;
            __syncthreads();
            if (tid < NPAT) {
                float S1 = 0.f, S2 = 0.f;
                #pragma unroll
                for (int s = 0; s < 4; ++s) {
                    int tt = tok_of(tid, s);
                    S1 += part[tt*4 + 0] + part[tt*4 + 2];
                    S2 += part[tt*4 + 1] + part[tt*4 + 3];
                }
                float mu  = S1 * (1.f/768.f);
                float var = S2 * (1.f/768.f) - mu*mu;
                stats[x*128 + tid]      = mu;
                stats[x*128 + 64 + tid] = rsqrtf(var + LN_EPS);
            }
            __syncthreads();
        }
    }

    const int mwin = win & 63;
    const float* mask_w = mask_g + (size_t)mwin * NPAT * NPAT;

    // ---------------- Phase 2: per-head attention ----------------
    for (int h = 0; h < NHEAD; ++h) {
        __syncthreads();   // prior AV reads / softmax reads done before restaging

        if (tid < 225) biash[tid] = btab[tid * NHEAD + h];

        // ---- stage Kh (row-major) and Vt (transposed) as normalized bf16 ----
        #pragma unroll
        for (int i = 0; i < 2; ++i) {
            int c   = tid * 2 + i;            // 0..1023 chunks of 8
            int p   = c >> 4;
            int scb = c & 15;
            int s   = scb >> 2;
            int co  = (scb & 3) * 8;
            int t   = tok_of(p, s);
            int chb = h * HDIM + co;

            // K
            {
                const float* kp = k_g + wbase + t*EMB + chb;
                s16x8 kk = ln_pack8(kp, muk[p], rsk[p],
                                    lnkw + s*EMB + chb, lnkb + s*EMB + chb, 1.0f);
                *(s16x8*)(smem + OFF_KH + p*256 + ((scb*16) ^ ((p & 7) << 4))) = kk;
            }
            // V (scatter into transposed layout)
            {
                const float* vp = v_g + wbase + t*EMB + chb;
                float vn[8];
                ln_f8(vp, muv[p], rsv[p], lnvw + s*EMB + chb, lnvb + s*EMB + chb, vn);
                #pragma unroll
                for (int j = 0; j < 8; ++j) {
                    int sc = scb*8 + j;
                    *(unsigned short*)(smem + OFF_VT + sc*128 + ((p*2) ^ ((sc & 7) << 4)))
                        = f2bf(vn[j]);
                }
            }
        }
        __syncthreads();

        // ---- QK^T : wave = (mstrip, nhalf) ----
        {
            int mstrip = wv >> 1, nhalf = wv & 1;
            int pr = mstrip*16 + (lane & 15);
            int cb = lane >> 4;
            float mu = muq[pr], rs = rsq[pr];
            f32x4 acc0 = {0.f,0.f,0.f,0.f};
            f32x4 acc1 = {0.f,0.f,0.f,0.f};
            #pragma unroll
            for (int ks = 0; ks < 4; ++ks) {
                int s = ks;
                int t = tok_of(pr, s);
                int chb = h*HDIM + cb*8;
                s16x8 af = ln_pack8(q_g + wbase + t*EMB + chb, mu, rs,
                                    lnqw + s*EMB + chb, lnqb + s*EMB + chb, SCALE);
                {
                    int row = (nhalf*2 + 0)*16 + (lane & 15);
                    s16x8 bf = *(const s16x8*)(smem + OFF_KH + row*256 +
                                  ((ks*64 + cb*16) ^ ((row & 7) << 4)));
                    acc0 = mfma16(af, bf, acc0);
                }
                {
                    int row = (nhalf*2 + 1)*16 + (lane & 15);
                    s16x8 bf = *(const s16x8*)(smem + OFF_KH + row*256 +
                                  ((ks*64 + cb*16) ^ ((row & 7) << 4)));
                    acc1 = mfma16(af, bf, acc1);
                }
            }
            float* Sb = (float*)(smem + OFF_SB);
            #pragma unroll
            for (int r = 0; r < 4; ++r) {
                int qr = mstrip*16 + (lane >> 4)*4 + r;
                Sb[qr*68 + (nhalf*2+0)*16 + (lane & 15)] = acc0[r];
                Sb[qr*68 + (nhalf*2+1)*16 + (lane & 15)] = acc1[r];
            }
        }
        __syncthreads();

        // ---- softmax (+bias +mask) : 8 threads per row ----
        {
            int qr = tid >> 3, j = tid & 7;
            const float* Sb = (const float*)(smem + OFF_SB);
            f32x4 s0 = *(const f32x4*)(Sb + qr*68 + j*8);
            f32x4 s1 = *(const f32x4*)(Sb + qr*68 + j*8 + 4);
            f32x4 m0 = *(const f32x4*)(mask_w + qr*64 + j*8);
            f32x4 m1 = *(const f32x4*)(mask_w + qr*64 + j*8 + 4);
            int qh = qr >> 3, qw = qr & 7;
            float vals[8];
            #pragma unroll
            for (int jj = 0; jj < 8; ++jj) {
                int kc = j*8 + jj;
                int idx = (qh - (kc >> 3) + 7)*15 + (qw - (kc & 7) + 7);
                float sv = (jj < 4 ? s0[jj] : s1[jj-4]) +
                           (jj < 4 ? m0[jj] : m1[jj-4]) + biash[idx];
                vals[jj] = sv;
            }
            float mx = vals[0];
            #pragma unroll
            for (int jj = 1; jj < 8; ++jj) mx = fmaxf(mx, vals[jj]);
            mx = fmaxf(mx, __shfl_xor(mx, 1));
            mx = fmaxf(mx, __shfl_xor(mx, 2));
            mx = fmaxf(mx, __shfl_xor(mx, 4));
            float sum = 0.f;
            #pragma unroll
            for (int jj = 0; jj < 8; ++jj) { vals[jj] = __expf(vals[jj] - mx); sum += vals[jj]; }
            sum += __shfl_xor(sum, 1);
            sum += __shfl_xor(sum, 2);
            sum += __shfl_xor(sum, 4);
            float rinv = 1.f / sum;
            s16x8 pv;
            #pragma unroll
            for (int jj = 0; jj < 8; ++jj) pv[jj] = (short)f2bf(vals[jj] * rinv);
            *(s16x8*)(smem + OFF_PB + qr*128 + ((j*16) ^ ((qr & 7) << 4))) = pv;
        }
        __syncthreads();

        // ---- P @ V : wave = (m, nset) covering out[64][128] ----
        {
            int m = wv >> 1, nset = wv & 1;
            int cb = lane >> 4;
            int prow = m*16 + (lane & 15);
            s16x8 ap0 = *(const s16x8*)(smem + OFF_PB + prow*128 +
                          ((0*64 + cb*16) ^ ((prow & 7) << 4)));
            s16x8 ap1 = *(const s16x8*)(smem + OFF_PB + prow*128 +
                          ((1*64 + cb*16) ^ ((prow & 7) << 4)));
            #pragma unroll
            for (int i = 0; i < 4; ++i) {
                int nt = nset*4 + i;
                int brow = nt*16 + (lane & 15);     // sc
                f32x4 acc = {0.f,0.f,0.f,0.f};
                s16x8 bf0 = *(const s16x8*)(smem + OFF_VT + brow*128 +
                              ((0*64 + cb*16) ^ ((brow & 7) << 4)));
                s16x8 bf1 = *(const s16x8*)(smem + OFF_VT + brow*128 +
                              ((1*64 + cb*16) ^ ((brow & 7) << 4)));
                acc = mfma16(ap0, bf0, acc);
                acc = mfma16(ap1, bf1, acc);
                // epilogue: scatter into OutPre (ungrouped token layout)
                int sc = nt*16 + (lane & 15);
                int s  = sc >> 5, c2 = sc & 31;
                int ch = h*HDIM + c2;
                #pragma unroll
                for (int r = 0; r < 4; ++r) {
                    int qp = m*16 + (lane >> 4)*4 + r;
                    int t  = tok_of(qp, s);
                    *(unsigned short*)(smem + OFF_PRE + t*384 + ((ch*2) ^ ((t & 7) << 4)))
                        = f2bf(acc[r]);
                }
            }
        }
    } // head loop

    // ---------------- Phase 3: projection (two 96-col halves) ----------------
    for (int np = 0; np < 2; ++np) {
        __syncthreads();    // OutPre complete / previous half's reads done
        // stage W[np*96 .. +96)[192] as bf16
        for (int c = tid; c < 96*24; c += 512) {
            int o = c / 24, cb8 = c % 24;
            const float* wp = pw + (size_t)(np*96 + o)*EMB + cb8*8;
            f32x4 a = *(const f32x4*)wp;
            f32x4 b = *(const f32x4*)(wp + 4);
            s16x8 w8;
            w8[0] = (short)f2bf(a[0]); w8[1] = (short)f2bf(a[1]);
            w8[2] = (short)f2bf(a[2]); w8[3] = (short)f2bf(a[3]);
            w8[4] = (short)f2bf(b[0]); w8[5] = (short)f2bf(b[1]);
            w8[6] = (short)f2bf(b[2]); w8[7] = (short)f2bf(b[3]);
            *(s16x8*)(smem + OFF_WL + o*384 + ((cb8*16) ^ ((o & 7) << 4))) = w8;
        }
        __syncthreads();

        int cb = lane >> 4;
        #pragma unroll
        for (int mi = 0; mi < 2; ++mi) {
            int mt = wv*2 + mi;
            int arow = mt*16 + (lane & 15);
            s16x8 af[6];
            #pragma unroll
            for (int ks = 0; ks < 6; ++ks) {
                af[ks] = *(const s16x8*)(smem + OFF_PRE + arow*384 +
                              ((ks*64 + cb*16) ^ ((arow & 7) << 4)));
            }
            #pragma unroll
            for (int nt = 0; nt < 6; ++nt) {
                int orow = nt*16 + (lane & 15);
                f32x4 acc = {0.f,0.f,0.f,0.f};
                #pragma unroll
                for (int ks = 0; ks < 6; ++ks) {
                    s16x8 bf = *(const s16x8*)(smem + OFF_WL + orow*384 +
                                  ((ks*64 + cb*16) ^ ((orow & 7) << 4)));
                    acc = mfma16(af[ks], bf, acc);
                }
                int oc = np*96 + nt*16 + (lane & 15);
                #pragma unroll
                for (int r = 0; r < 4; ++r) {
                    int trow = mt*16 + (lane >> 4)*4 + r;
                    out_g[wbase + trow*EMB + oc] = acc[r];
                }
            }
        }
    }
}

extern "C" void kernel_launch(void* const* d_in, const int* in_sizes, int n_in,
                              void* d_out, int out_size, void* d_ws, size_t ws_size,
                              hipStream_t stream) {
    (void)in_sizes; (void)n_in; (void)out_size; (void)d_ws; (void)ws_size;
    dwa_kernel<<<dim3(NWIN), dim3(512), 0, stream>>>(
        (const float*)d_in[0],  (const float*)d_in[1],  (const float*)d_in[2],
        (const float*)d_in[3],  (const float*)d_in[4],  (const float*)d_in[5],
        (const float*)d_in[6],  (const float*)d_in[7],  (const float*)d_in[8],
        (const float*)d_in[9],  (const float*)d_in[10], (const float*)d_in[11],
        (float*)d_out);
}